// Round 7
// baseline (368.592 us; speedup 1.0000x reference)
//
#include <hip/hip_runtime.h>
#include <hip/hip_bf16.h>
#include <math.h>
#include <stdint.h>

#define B_    32
#define S_    512
#define H_    768
#define NH_   12
#define HD_   64
#define NCOL_ 32
#define M_    (B_*S_)   // 16384

typedef __bf16 bf16;
typedef __bf16 bf16x8 __attribute__((ext_vector_type(8)));
typedef __bf16 bf16x4 __attribute__((ext_vector_type(4)));
typedef float  f32x4  __attribute__((ext_vector_type(4)));

// ---------------------------------------------------------------------------
// async global->LDS 16B copy (global_load_lds_dwordx4)
// ---------------------------------------------------------------------------
__device__ __forceinline__ void async_load16(const void* g, void* l) {
    __builtin_amdgcn_global_load_lds(
        (__attribute__((address_space(1))) unsigned int*)g,
        (__attribute__((address_space(3))) unsigned int*)l, 16, 0, 0);
}

// fp32 -> bf16x8 converting load (32B in)
__device__ __forceinline__ bf16x8 cvt8(const float* p) {
    const float4* fp = (const float4*)p;
    float4 x = fp[0], y = fp[1];
    bf16x8 r;
    r[0] = (bf16)x.x; r[1] = (bf16)x.y; r[2] = (bf16)x.z; r[3] = (bf16)x.w;
    r[4] = (bf16)y.x; r[5] = (bf16)y.y; r[6] = (bf16)y.z; r[7] = (bf16)y.w;
    return r;
}

// ---------------------------------------------------------------------------
// fused convert: hidden->hbf, gather->hcol, weights->wpack, qkv bias pack
// ---------------------------------------------------------------------------
__global__ __launch_bounds__(256) void cvt_kernel(
    const float* __restrict__ hidden, const float* __restrict__ ce,
    const int* __restrict__ cc, const int* __restrict__ vm,
    const float* __restrict__ Wd, const float* __restrict__ Wc,
    const float* __restrict__ Wq, const float* __restrict__ Wk,
    const float* __restrict__ Wv, const float* __restrict__ Wo,
    const float* __restrict__ bq, const float* __restrict__ bk,
    const float* __restrict__ bv,
    bf16* __restrict__ hbf, bf16* __restrict__ hcol,
    bf16* __restrict__ wpack, float* __restrict__ bqkv)
{
    int blk = blockIdx.x;
    if (blk < 6144) {
        int id = blk * 256 + threadIdx.x;
        int row = id / 96, c = id - row * 96;
        *(bf16x8*)&hbf[(long)row * H_ + c * 8] = cvt8(hidden + (long)row * H_ + c * 8);
    } else if (blk < 12288) {
        int id = (blk - 6144) * 256 + threadIdx.x;
        int row = id / 96, c = id - row * 96;
        int b = row >> 9;
        int m = vm[row];
        bf16x8 val;
#pragma unroll
        for (int i = 0; i < 8; i++) val[i] = (bf16)0.0f;
        if (m > 0) {
            int col = m - 1;
            if (cc[b * NCOL_ + col] == 1)
                val = cvt8(ce + ((long)(b * NCOL_ + col)) * H_ + c * 8);
        }
        *(bf16x8*)&hcol[(long)row * H_ + c * 8] = val;
    } else {
        int id = (blk - 12288) * 256 + threadIdx.x;
        if (id < 442368) {
            const float* src;
            int r = id;
            if      (r < 73728)  { src = Wd; }
            else if (r < 147456) { src = Wc; r -= 73728; }
            else if (r < 221184) { src = Wq; r -= 147456; }
            else if (r < 294912) { src = Wk; r -= 221184; }
            else if (r < 368640) { src = Wv; r -= 294912; }
            else                 { src = Wo; r -= 368640; }
            *(bf16x8*)&wpack[(long)id * 8] = cvt8(src + (long)r * 8);
        } else if (id < 442656) {
            int j0 = (id - 442368) * 8;
#pragma unroll
            for (int i = 0; i < 8; i++) {
                int j = j0 + i;
                float v = (j < 768) ? bq[j] : (j < 1536) ? bk[j - 768] : bv[j - 1536];
                bqkv[j] = v;
            }
        }
    }
}

// ---------------------------------------------------------------------------
// QKV GEMM: C[m,n] = sum_k A[m,k]*W[n,k] + bias, n in [0,2304).
// BM=256 BN=128 BK=32, 512 threads = 8 waves (4x2, 64x64/wave). Measured
// 73us (round 6): triple-buffered 72KB LDS (2 blocks/CU), counted vmcnt(3),
// ONE barrier/K-tile, 2-bit XOR chunk swizzle, LDS-pack epilogue (WRITE_SIZE
// = exact logical 72MB; RFO gone). UNCHANGED from round 6.
// ---------------------------------------------------------------------------
__global__ __launch_bounds__(512, 4) void gemm_qkv(
    const bf16* __restrict__ A, const bf16* __restrict__ Bw,
    const float* __restrict__ bias, bf16* __restrict__ out)
{
    // 72KB: SA = LB[0 .. 3*8192), SB = LB[24576 .. +3*4096).
    // Epilogue scratch: 8 waves x 64x72 elems = 36864 elems (exact fit).
    __shared__ __align__(16) bf16 LB[36864];

    const int tid  = threadIdx.x;
    const int lane = tid & 63;
    const int wave = tid >> 6;
    const int wr   = wave >> 1;          // 0..3: 64-row band of A
    const int wc   = wave & 1;           // 0..1: 64-col band of B
    const int quad = lane >> 4;
    const int ln16 = lane & 15;
    const int m0   = blockIdx.x * 256;
    const int n0   = blockIdx.y * 128;

    int arow[2], acol[2];
#pragma unroll
    for (int q = 0; q < 2; q++) {
        int l = q * 512 + tid;
        int row = l >> 2;
        arow[q] = row;
        acol[q] = ((l & 3) ^ ((row >> 1) & 3)) * 8;
    }
    const int brow = tid >> 2;
    const int bcol = ((tid & 3) ^ ((brow >> 1) & 3)) * 8;

    auto stage = [&](int kt, int bsel) {
        int kk = kt * 32;
        const bf16* ag = A + kk;
        const bf16* bg = Bw + kk;
        bf16* SAb = &LB[bsel * 8192];
        bf16* SBb = &LB[24576 + bsel * 4096];
        async_load16(ag + (long)(m0 + arow[0]) * H_ + acol[0], SAb + tid * 8);
        async_load16(ag + (long)(m0 + arow[1]) * H_ + acol[1], SAb + 4096 + tid * 8);
        async_load16(bg + (long)(n0 + brow)    * H_ + bcol,    SBb + tid * 8);
    };

    f32x4 acc[4][4];
    const f32x4 zero4 = {0.f, 0.f, 0.f, 0.f};
#pragma unroll
    for (int i = 0; i < 4; i++)
#pragma unroll
        for (int j = 0; j < 4; j++) acc[i][j] = zero4;

    const int s4 = (ln16 >> 1) & 3;
    int aoff[4], boff[4];
#pragma unroll
    for (int i = 0; i < 4; i++) {
        aoff[i] = (wr * 64 + i * 16 + ln16) * 32 + (quad ^ s4) * 8;
        boff[i] = (wc * 64 + i * 16 + ln16) * 32 + (quad ^ s4) * 8;
    }

    const int nt = 24;                    // K = 768

    stage(0, 0);
    stage(1, 1);
    asm volatile("s_waitcnt vmcnt(3)" ::: "memory");
    __builtin_amdgcn_sched_barrier(0);
    __builtin_amdgcn_s_barrier();

    int bs = 0;
    for (int t = 0; t < nt; ++t) {
        const int ps = (bs + 2 >= 3) ? bs - 1 : bs + 2;   // (t+2)%3

        bf16x8 af[4], bfr[4];
#pragma unroll
        for (int i = 0; i < 4; i++) af[i]  = *(const bf16x8*)&LB[bs * 8192 + aoff[i]];
#pragma unroll
        for (int j = 0; j < 4; j++) bfr[j] = *(const bf16x8*)&LB[24576 + bs * 4096 + boff[j]];
        if (t + 2 < nt) stage(t + 2, ps);

        __builtin_amdgcn_s_setprio(1);
#pragma unroll
        for (int i = 0; i < 4; i++)
#pragma unroll
            for (int j = 0; j < 4; j++)
                acc[i][j] = __builtin_amdgcn_mfma_f32_16x16x32_bf16(af[i], bfr[j], acc[i][j], 0, 0, 0);
        __builtin_amdgcn_s_setprio(0);

        if (t + 2 < nt)       { asm volatile("s_waitcnt vmcnt(3)" ::: "memory"); }
        else if (t + 1 < nt)  { asm volatile("s_waitcnt vmcnt(0)" ::: "memory"); }
        __builtin_amdgcn_sched_barrier(0);
        if (t + 1 < nt) __builtin_amdgcn_s_barrier();
        bs = (bs + 1 == 3) ? 0 : bs + 1;
    }

    // ---- epilogue: LDS-pack then coalesced 128B writes ----
    __syncthreads();                       // all waves done reading SA/SB
    bf16* scr = &LB[wave * 4608];          // 64 x 72 elems per wave

    const int cs0  = n0 + wc * 64;         // 64-aligned -> whole band = one head
    const int sec  = (cs0 >= 1536) ? 2 : ((cs0 >= 768) ? 1 : 0);
    const int head = (cs0 - sec * 768) >> 6;
    bf16* dst = out + (long)sec * M_ * H_;

#pragma unroll
    for (int j = 0; j < 4; j++) {
        const int d_loc = j * 16 + ln16;
        const float bj = bias[cs0 + d_loc];
#pragma unroll
        for (int i = 0; i < 4; i++) {
#pragma unroll
            for (int r = 0; r < 4; r++) {
                const int s_loc = i * 16 + quad * 4 + r;
                const float v = acc[i][j][r] + bj;
                scr[(sec == 2) ? (d_loc * 72 + s_loc) : (s_loc * 72 + d_loc)] = (bf16)v;
            }
        }
    }
    asm volatile("s_waitcnt lgkmcnt(0)" ::: "memory");
    __builtin_amdgcn_sched_barrier(0);

    const int g8 = lane >> 3;              // 0..7
    const int o8 = (lane & 7) * 8;         // 0..56
    if (sec < 2) {
        // [B,NH,S,HD]: 8-lane group writes one row's 128B; 8 rows per it-step
#pragma unroll
        for (int it = 0; it < 8; it++) {
            const int s_loc = it * 8 + g8;
            const int row_s = m0 + wr * 64 + s_loc;
            const int b = row_s >> 9, s = row_s & 511;
            *(bf16x8*)&dst[(((long)(b * NH_ + head)) * S_ + s) * HD_ + o8] =
                *(const bf16x8*)&scr[s_loc * 72 + o8];
        }
    } else {
        // V^T [B,NH,HD,S]: 64-row window is 64-aligned -> single b, s_base
        const int row0 = m0 + wr * 64;
        const int b = row0 >> 9, sb = row0 & 511;
#pragma unroll
        for (int it = 0; it < 8; it++) {
            const int d_loc = it * 8 + g8;
            *(bf16x8*)&dst[(((long)(b * NH_ + head)) * HD_ + d_loc) * S_ + sb + o8] =
                *(const bf16x8*)&scr[d_loc * 72 + o8];
        }
    }
}

// ---------------------------------------------------------------------------
// GEMM C[m,n] = sum_k A[m,k]*Bw[n,k], bf16, lda=ldb=768. MODE 0: gelu(+b1+b2);
// MODE 2: +b1+resid (in-place ok). BM=128 BN=128 BK=32, 256 threads = 4 waves
// (2x2, 64x64/wave). Triple-buffer 48KB -> 3 blocks/CU; grids (128,6)=768 =
// exact residency multiple. Loop = round-5/6 verified code.
//
// NEW (round 7): LDS-pack epilogue (technique measured-win on gemm_qkv in
// round 6: WRITE_SIZE -> exact logical). The scalar epilogue's 32B-segment
// stores (4 instrs per 128B line) forced read-for-ownership; pack the wave's
// 64x64 tile into the dead staging LDS (stride 72) and write full 128B runs.
// ---------------------------------------------------------------------------
template<int MODE>
__global__ __launch_bounds__(256, 3) void gemm_bt(
    const bf16* __restrict__ A0, const bf16* __restrict__ A1,
    const bf16* __restrict__ B0, const bf16* __restrict__ B1,
    const float* __restrict__ bias1, const float* __restrict__ bias2,
    const bf16* __restrict__ resid, bf16* __restrict__ out,
    int K, int KSPLIT)
{
    // 48KB flat: SA = LB[0 .. 3*4096), SB = LB[12288 .. +3*4096).
    // Epilogue scratch: 4 waves x 64x72 = 18432 elems (fits in 24576).
    __shared__ __align__(16) bf16 LB[24576];

    const int tid  = threadIdx.x;
    const int lane = tid & 63;
    const int wave = tid >> 6;
    const int wr   = wave >> 1;
    const int wc   = wave & 1;
    const int quad = lane >> 4;
    const int ln16 = lane & 15;
    const int m0   = blockIdx.x * 128;
    const int n0   = blockIdx.y * 128;

    int arow[2], acol[2];
#pragma unroll
    for (int q = 0; q < 2; q++) {
        int l = q * 256 + tid;
        int row = l >> 2;
        arow[q] = row;
        acol[q] = ((l & 3) ^ ((row >> 1) & 3)) * 8;
    }

    auto stage = [&](int kt, int bsel) {
        int kk = kt * 32;
        const bf16* ag = (kk < KSPLIT) ? A0 + kk : A1 + (kk - KSPLIT);
        const bf16* bg = (kk < KSPLIT) ? B0 + kk : B1 + (kk - KSPLIT);
        bf16* SAb = &LB[bsel * 4096];
        bf16* SBb = &LB[12288 + bsel * 4096];
        async_load16(ag + (long)(m0 + arow[0]) * H_ + acol[0], SAb + tid * 8);
        async_load16(ag + (long)(m0 + arow[1]) * H_ + acol[1], SAb + 2048 + tid * 8);
        async_load16(bg + (long)(n0 + arow[0]) * H_ + acol[0], SBb + tid * 8);
        async_load16(bg + (long)(n0 + arow[1]) * H_ + acol[1], SBb + 2048 + tid * 8);
    };

    f32x4 acc[4][4];
    const f32x4 zero4 = {0.f, 0.f, 0.f, 0.f};
#pragma unroll
    for (int i = 0; i < 4; i++)
#pragma unroll
        for (int j = 0; j < 4; j++) acc[i][j] = zero4;

    const int s4 = (ln16 >> 1) & 3;
    int aoff[4], boff[4];
#pragma unroll
    for (int i = 0; i < 4; i++) {
        aoff[i] = (wr * 64 + i * 16 + ln16) * 32 + (quad ^ s4) * 8;
        boff[i] = (wc * 64 + i * 16 + ln16) * 32 + (quad ^ s4) * 8;
    }

    const int nt = K >> 5;

    stage(0, 0);
    stage(1, 1);
    asm volatile("s_waitcnt vmcnt(4)" ::: "memory");
    __builtin_amdgcn_sched_barrier(0);
    __builtin_amdgcn_s_barrier();

    int bs = 0;
    for (int t = 0; t < nt; ++t) {
        const int ps = (bs + 2 >= 3) ? bs - 1 : bs + 2;

        bf16x8 af[4], bfr[4];
#pragma unroll
        for (int i = 0; i < 4; i++) af[i]  = *(const bf16x8*)&LB[bs * 4096 + aoff[i]];
#pragma unroll
        for (int j = 0; j < 4; j++) bfr[j] = *(const bf16x8*)&LB[12288 + bs * 4096 + boff[j]];
        if (t + 2 < nt) stage(t + 2, ps);

        __builtin_amdgcn_s_setprio(1);
#pragma unroll
        for (int i = 0; i < 4; i++)
#pragma unroll
            for (int j = 0; j < 4; j++)
                acc[i][j] = __builtin_amdgcn_mfma_f32_16x16x32_bf16(af[i], bfr[j], acc[i][j], 0, 0, 0);
        __builtin_amdgcn_s_setprio(0);

        if (t + 2 < nt)       { asm volatile("s_waitcnt vmcnt(4)" ::: "memory"); }
        else if (t + 1 < nt)  { asm volatile("s_waitcnt vmcnt(0)" ::: "memory"); }
        __builtin_amdgcn_sched_barrier(0);
        if (t + 1 < nt) __builtin_amdgcn_s_barrier();
        bs = (bs + 1 == 3) ? 0 : bs + 1;
    }

    // ---- epilogue: LDS-pack then coalesced 128B writes ----
    __syncthreads();                       // all waves done reading SA/SB
    bf16* scr = &LB[wave * 4608];          // 64 x 72 elems per wave

    const int row0 = m0 + wr * 64;
    const int col0 = n0 + wc * 64;

#pragma unroll
    for (int j = 0; j < 4; j++) {
        const int d_loc = j * 16 + ln16;
        float bias = bias1[col0 + d_loc];
        if (MODE == 0) bias += bias2[col0 + d_loc];
#pragma unroll
        for (int i = 0; i < 4; i++) {
#pragma unroll
            for (int r = 0; r < 4; r++) {
                const int s_loc = i * 16 + quad * 4 + r;
                float v = acc[i][j][r] + bias;
                if (MODE == 0) {
                    v = 0.5f * v * (1.0f + erff(v * 0.70710678118654752f));
                } else {
                    v += (float)resid[(long)(row0 + s_loc) * H_ + col0 + d_loc];
                }
                scr[s_loc * 72 + d_loc] = (bf16)v;
            }
        }
    }
    asm volatile("s_waitcnt lgkmcnt(0)" ::: "memory");
    __builtin_amdgcn_sched_barrier(0);

    const int g8 = lane >> 3;              // 0..7
    const int o8 = (lane & 7) * 8;         // 0..56
#pragma unroll
    for (int it = 0; it < 8; it++) {
        const int s_loc = it * 8 + g8;
        *(bf16x8*)&out[(long)(row0 + s_loc) * H_ + col0 + o8] =
            *(const bf16x8*)&scr[s_loc * 72 + o8];
    }
}

// ---------------------------------------------------------------------------
// flash attention, transposed-score form (unchanged).
// ---------------------------------------------------------------------------
#define QP 72   // LDS row stride (elems): 144 B, 16B-aligned

__global__ __launch_bounds__(256) void attn_kernel(
    const bf16* __restrict__ q, const bf16* __restrict__ k,
    const bf16* __restrict__ vt, bf16* __restrict__ ctx)
{
    __shared__ __align__(16) bf16 Qs[64 * QP];
    __shared__ __align__(16) bf16 Ks[64 * QP];
    __shared__ __align__(16) bf16 Vt[64 * QP];      // V^T chunk: [d][t]
    __shared__ __align__(16) bf16 Ps[4][16 * QP];   // per-wave P: [q][t]

    const int tid  = threadIdx.x;
    const int lane = tid & 63;
    const int w    = tid >> 6;
    const int quad = lane >> 4;
    const int ln16 = lane & 15;

    const int bid = blockIdx.x;
    const int qt  = bid / 384;          // qt-major: same g -> same XCD (384%8==0)
    const int g   = bid - qt * 384;
    const int b   = g / 12;
    const int h   = g - b * 12;
    const long base = ((long)(b * NH_ + h)) * S_ * HD_;

    const int r0 = tid >> 2;            // row 0..63
    const int e0 = (tid & 3) * 16;      // col elems 0,16,32,48

    {
        const bf16* qg = q + base + (long)qt * 64 * HD_;
        *(uint4*)&Qs[r0 * QP + e0]     = *(const uint4*)&qg[r0 * HD_ + e0];
        *(uint4*)&Qs[r0 * QP + e0 + 8] = *(const uint4*)&qg[r0 * HD_ + e0 + 8];
    }
    const bf16* kg = k  + base;
    const bf16* vg = vt + base;
    uint4 kr0 = *(const uint4*)&kg[r0 * HD_ + e0];
    uint4 kr1 = *(const uint4*)&kg[r0 * HD_ + e0 + 8];
    uint4 vr0 = *(const uint4*)&vg[(long)r0 * S_ + e0];
    uint4 vr1 = *(const uint4*)&vg[(long)r0 * S_ + e0 + 8];
    __syncthreads();

    const bf16x8 bq0 = *(const bf16x8*)&Qs[(w * 16 + ln16) * QP + quad * 8];
    const bf16x8 bq1 = *(const bf16x8*)&Qs[(w * 16 + ln16) * QP + 32 + quad * 8];

    f32x4 O[4];
    const f32x4 zero4 = {0.f, 0.f, 0.f, 0.f};
#pragma unroll
    for (int t = 0; t < 4; t++) O[t] = zero4;
    float mo = -1e30f, l = 0.f;

    for (int kc = 0; kc < 8; kc++) {
        __syncthreads();
        *(uint4*)&Ks[r0 * QP + e0]     = kr0;
        *(uint4*)&Ks[r0 * QP + e0 + 8] = kr1;
        *(uint4*)&Vt[r0 * QP + e0]     = vr0;
        *(uint4*)&Vt[r0 * QP + e0 + 8] = vr1;
        {
            int kcn = (kc < 7) ? kc + 1 : 7;
            kr0 = *(const uint4*)&kg[(long)kcn * 64 * HD_ + r0 * HD_ + e0];
            kr1 = *(const uint4*)&kg[(long)kcn * 64 * HD_ + r0 * HD_ + e0 + 8];
            vr0 = *(const uint4*)&vg[(long)r0 * S_ + kcn * 64 + e0];
            vr1 = *(const uint4*)&vg[(long)r0 * S_ + kcn * 64 + e0 + 8];
        }
        __syncthreads();

        f32x4 sc[4];
#pragma unroll
        for (int i = 0; i < 4; i++) {
            bf16x8 a0 = *(const bf16x8*)&Ks[(i * 16 + ln16) * QP + quad * 8];
            bf16x8 a1 = *(const bf16x8*)&Ks[(i * 16 + ln16) * QP + 32 + quad * 8];
            sc[i] = zero4;
            sc[i] = __builtin_amdgcn_mfma_f32_16x16x32_bf16(a0, bq0, sc[i], 0, 0, 0);
            sc[i] = __builtin_amdgcn_mfma_f32_16x16x32_bf16(a1, bq1, sc[i], 0, 0, 0);
        }

        float cm = -1e30f;
#pragma unroll
        for (int i = 0; i < 4; i++)
#pragma unroll
            for (int r = 0; r < 4; r++) {
                float s = sc[i][r] * 0.125f;
                sc[i][r] = s;
                cm = fmaxf(cm, s);
            }
        cm = fmaxf(cm, __shfl_xor(cm, 16));
        cm = fmaxf(cm, __shfl_xor(cm, 32));
        float mn = fmaxf(mo, cm);
        float alpha = __expf(mo - mn);
        float rs = 0.f;
#pragma unroll
        for (int i = 0; i < 4; i++) {
            bf16x4 pk;
#pragma unroll
            for (int r = 0; r < 4; r++) {
                float p = __expf(sc[i][r] - mn);
                rs += p;
                pk[r] = (bf16)p;
            }
            *(bf16x4*)&Ps[w][ln16 * QP + i * 16 + quad * 4] = pk;
        }
        rs += __shfl_xor(rs, 16);
        rs += __shfl_xor(rs, 32);
        l  = l * alpha + rs;
        mo = mn;
#pragma unroll
        for (int t = 0; t < 4; t++)
#pragma unroll
            for (int r = 0; r < 4; r++) O[t][r] *= alpha;

        bf16x8 bp0 = *(const bf16x8*)&Ps[w][ln16 * QP + quad * 8];
        bf16x8 bp1 = *(const bf16x8*)&Ps[w][ln16 * QP + 32 + quad * 8];
#pragma unroll
        for (int dt = 0; dt < 4; dt++) {
            bf16x8 a0 = *(const bf16x8*)&Vt[(dt * 16 + ln16) * QP + quad * 8];
            bf16x8 a1 = *(const bf16x8*)&Vt[(dt * 16 + ln16) * QP + 32 + quad * 8];
            O[dt] = __builtin_amdgcn_mfma_f32_16x16x32_bf16(a0, bp0, O[dt], 0, 0, 0);
            O[dt] = __builtin_amdgcn_mfma_f32_16x16x32_bf16(a1, bp1, O[dt], 0, 0, 0);
        }
    }

    {
        float inv = 1.0f / l;
#pragma unroll
        for (int dt = 0; dt < 4; dt++) {
            bf16x4 ov;
#pragma unroll
            for (int r = 0; r < 4; r++) ov[r] = (bf16)(O[dt][r] * inv);
            *(bf16x4*)&Qs[(w * 16 + ln16) * QP + dt * 16 + quad * 4] = ov;
        }
    }
    __syncthreads();
    {
        uint4 o0 = *(const uint4*)&Qs[r0 * QP + e0];
        uint4 o1 = *(const uint4*)&Qs[r0 * QP + e0 + 8];
        bf16* cg = ctx + ((long)(b * S_ + qt * 64 + r0)) * H_ + h * HD_;
        *(uint4*)&cg[e0]     = o0;
        *(uint4*)&cg[e0 + 8] = o1;
    }
}

// ---------------------------------------------------------------------------
// layernorm: one wave per row; bf16 in, fp32 out
// ---------------------------------------------------------------------------
__global__ __launch_bounds__(256) void ln_kernel(
    const bf16* __restrict__ y, const float* __restrict__ g,
    const float* __restrict__ be, float* __restrict__ out)
{
    const int lane = threadIdx.x & 63;
    const int w    = threadIdx.x >> 6;
    const long row = (long)blockIdx.x * 4 + w;
    const bf16* yr = y + row * H_;

    float x[12];
    float sum = 0.f, ss = 0.f;
#pragma unroll
    for (int j = 0; j < 12; j++) {
        x[j] = (float)yr[j * 64 + lane];
        sum += x[j];
        ss  += x[j] * x[j];
    }
#pragma unroll
    for (int m = 1; m < 64; m <<= 1) {
        sum += __shfl_xor(sum, m);
        ss  += __shfl_xor(ss, m);
    }
    const float mu  = sum * (1.0f / 768.0f);
    float var = ss * (1.0f / 768.0f) - mu * mu;
    const float rs = rsqrtf(fmaxf(var, 0.f) + 1e-12f);
#pragma unroll
    for (int j = 0; j < 12; j++) {
        int c = j * 64 + lane;
        out[row * H_ + c] = (x[j] - mu) * rs * g[c] + be[c];
    }
}

// ---------------------------------------------------------------------------
extern "C" void kernel_launch(void* const* d_in, const int* in_sizes, int n_in,
                              void* d_out, int out_size, void* d_ws, size_t ws_size,
                              hipStream_t stream)
{
    const float* hidden = (const float*)d_in[0];
    const float* ce     = (const float*)d_in[1];
    const int*   cc     = (const int*)d_in[2];
    const int*   vm     = (const int*)d_in[3];
    const float* Wd     = (const float*)d_in[4];
    const float* bd     = (const float*)d_in[5];
    const float* Wc     = (const float*)d_in[6];
    const float* bc     = (const float*)d_in[7];
    const float* Wq     = (const float*)d_in[8];
    const float* bq     = (const float*)d_in[9];
    const float* Wk     = (const float*)d_in[10];
    const float* bk     = (const float*)d_in[11];
    const float* Wv     = (const float*)d_in[12];
    const float* bv     = (const float*)d_in[13];
    const float* Wo     = (const float*)d_in[14];
    const float* bo     = (const float*)d_in[15];
    const float* lng    = (const float*)d_in[16];
    const float* lnb    = (const float*)d_in[17];

    // ---- workspace layout (bf16 elems; total ~102.8 MB) ----
    const long NE = (long)M_ * H_;
    bf16* ws   = (bf16*)d_ws;
    bf16* hbuf = ws;                          // gelu out / resid / y
    bf16* qkv  = ws + NE;                     // qb,kb,vb contiguous
    bf16* hbf  = qkv;                         // hbf over qb (dead before QKV writes)
    bf16* hcol = qkv + NE;                    // hcol over kb
    bf16* qb   = qkv;
    bf16* kb   = qkv + NE;
    bf16* vb   = qkv + 2 * NE;                // V^T layout [B,NH,HD,S]
    bf16* wpack = ws + 4 * NE;
    const bf16* Wd_b  = wpack;
    const bf16* Wc_b  = wpack + 589824;
    const bf16* Wq_b  = wpack + 1179648;      // Wq,Wk,Wv contiguous: 2304x768
    const bf16* Wo_b  = wpack + 2949120;
    float* bqkv = (float*)(wpack + 3538944);
    bf16* ctx = (bf16*)d_out;                 // borrow d_out (dead before LN)

    cvt_kernel<<<14018, 256, 0, stream>>>(hidden, ce, cc, vm, Wd, Wc, Wq, Wk, Wv, Wo,
                                          bq, bk, bv, hbf, hcol, wpack, bqkv);

    dim3 g6(M_ / 128, 6);
    gemm_bt<0><<<g6, 256, 0, stream>>>(hbf, hcol, Wd_b, Wc_b, bd, bc, nullptr, hbuf, 2 * H_, H_);
    gemm_qkv<<<dim3(M_ / 256, 18), 512, 0, stream>>>(hbuf, Wq_b, bqkv, qkv);
    attn_kernel<<<3072, 256, 0, stream>>>(qb, kb, vb, ctx);
    gemm_bt<2><<<g6, 256, 0, stream>>>(ctx, ctx, Wo_b, Wo_b, bo, nullptr, hbuf, hbuf, H_, H_);
    ln_kernel<<<M_ / 4, 256, 0, stream>>>(hbuf, lng, lnb, (float*)d_out);
}

// Round 8
// 366.544 us; speedup vs baseline: 1.0056x; 1.0056x over previous
//
#include <hip/hip_runtime.h>
#include <hip/hip_bf16.h>
#include <math.h>
#include <stdint.h>

#define B_    32
#define S_    512
#define H_    768
#define NH_   12
#define HD_   64
#define NCOL_ 32
#define M_    (B_*S_)   // 16384

typedef __bf16 bf16;
typedef __bf16 bf16x8 __attribute__((ext_vector_type(8)));
typedef __bf16 bf16x4 __attribute__((ext_vector_type(4)));
typedef float  f32x4  __attribute__((ext_vector_type(4)));

// ---------------------------------------------------------------------------
// async global->LDS 16B copy (global_load_lds_dwordx4)
// ---------------------------------------------------------------------------
__device__ __forceinline__ void async_load16(const void* g, void* l) {
    __builtin_amdgcn_global_load_lds(
        (__attribute__((address_space(1))) unsigned int*)g,
        (__attribute__((address_space(3))) unsigned int*)l, 16, 0, 0);
}

// fp32 -> bf16x8 converting load (32B in)
__device__ __forceinline__ bf16x8 cvt8(const float* p) {
    const float4* fp = (const float4*)p;
    float4 x = fp[0], y = fp[1];
    bf16x8 r;
    r[0] = (bf16)x.x; r[1] = (bf16)x.y; r[2] = (bf16)x.z; r[3] = (bf16)x.w;
    r[4] = (bf16)y.x; r[5] = (bf16)y.y; r[6] = (bf16)y.z; r[7] = (bf16)y.w;
    return r;
}

// ---------------------------------------------------------------------------
// fused convert: hidden->hbf, gather->hcol, weights->wpack, qkv bias pack
// ---------------------------------------------------------------------------
__global__ __launch_bounds__(256) void cvt_kernel(
    const float* __restrict__ hidden, const float* __restrict__ ce,
    const int* __restrict__ cc, const int* __restrict__ vm,
    const float* __restrict__ Wd, const float* __restrict__ Wc,
    const float* __restrict__ Wq, const float* __restrict__ Wk,
    const float* __restrict__ Wv, const float* __restrict__ Wo,
    const float* __restrict__ bq, const float* __restrict__ bk,
    const float* __restrict__ bv,
    bf16* __restrict__ hbf, bf16* __restrict__ hcol,
    bf16* __restrict__ wpack, float* __restrict__ bqkv)
{
    int blk = blockIdx.x;
    if (blk < 6144) {
        int id = blk * 256 + threadIdx.x;
        int row = id / 96, c = id - row * 96;
        *(bf16x8*)&hbf[(long)row * H_ + c * 8] = cvt8(hidden + (long)row * H_ + c * 8);
    } else if (blk < 12288) {
        int id = (blk - 6144) * 256 + threadIdx.x;
        int row = id / 96, c = id - row * 96;
        int b = row >> 9;
        int m = vm[row];
        bf16x8 val;
#pragma unroll
        for (int i = 0; i < 8; i++) val[i] = (bf16)0.0f;
        if (m > 0) {
            int col = m - 1;
            if (cc[b * NCOL_ + col] == 1)
                val = cvt8(ce + ((long)(b * NCOL_ + col)) * H_ + c * 8);
        }
        *(bf16x8*)&hcol[(long)row * H_ + c * 8] = val;
    } else {
        int id = (blk - 12288) * 256 + threadIdx.x;
        if (id < 442368) {
            const float* src;
            int r = id;
            if      (r < 73728)  { src = Wd; }
            else if (r < 147456) { src = Wc; r -= 73728; }
            else if (r < 221184) { src = Wq; r -= 147456; }
            else if (r < 294912) { src = Wk; r -= 221184; }
            else if (r < 368640) { src = Wv; r -= 294912; }
            else                 { src = Wo; r -= 368640; }
            *(bf16x8*)&wpack[(long)id * 8] = cvt8(src + (long)r * 8);
        } else if (id < 442656) {
            int j0 = (id - 442368) * 8;
#pragma unroll
            for (int i = 0; i < 8; i++) {
                int j = j0 + i;
                float v = (j < 768) ? bq[j] : (j < 1536) ? bk[j - 768] : bv[j - 1536];
                bqkv[j] = v;
            }
        }
    }
}

// ---------------------------------------------------------------------------
// QKV GEMM: C[m,n] = sum_k A[m,k]*W[n,k] + bias, n in [0,2304).
// BM=256 BN=128 BK=32, 512 threads = 8 waves (4x2, 64x64/wave). Measured
// 71.6us: triple-buffered 72KB LDS (2 blocks/CU), counted vmcnt(3), ONE
// barrier/K-tile, 2-bit XOR chunk swizzle, LDS-pack epilogue (WRITE_SIZE =
// exact logical 72MB; RFO gone). UNCHANGED (measured best).
// ---------------------------------------------------------------------------
__global__ __launch_bounds__(512, 4) void gemm_qkv(
    const bf16* __restrict__ A, const bf16* __restrict__ Bw,
    const float* __restrict__ bias, bf16* __restrict__ out)
{
    // 72KB: SA = LB[0 .. 3*8192), SB = LB[24576 .. +3*4096).
    // Epilogue scratch: 8 waves x 64x72 elems = 36864 elems (exact fit).
    __shared__ __align__(16) bf16 LB[36864];

    const int tid  = threadIdx.x;
    const int lane = tid & 63;
    const int wave = tid >> 6;
    const int wr   = wave >> 1;          // 0..3: 64-row band of A
    const int wc   = wave & 1;           // 0..1: 64-col band of B
    const int quad = lane >> 4;
    const int ln16 = lane & 15;
    const int m0   = blockIdx.x * 256;
    const int n0   = blockIdx.y * 128;

    int arow[2], acol[2];
#pragma unroll
    for (int q = 0; q < 2; q++) {
        int l = q * 512 + tid;
        int row = l >> 2;
        arow[q] = row;
        acol[q] = ((l & 3) ^ ((row >> 1) & 3)) * 8;
    }
    const int brow = tid >> 2;
    const int bcol = ((tid & 3) ^ ((brow >> 1) & 3)) * 8;

    auto stage = [&](int kt, int bsel) {
        int kk = kt * 32;
        const bf16* ag = A + kk;
        const bf16* bg = Bw + kk;
        bf16* SAb = &LB[bsel * 8192];
        bf16* SBb = &LB[24576 + bsel * 4096];
        async_load16(ag + (long)(m0 + arow[0]) * H_ + acol[0], SAb + tid * 8);
        async_load16(ag + (long)(m0 + arow[1]) * H_ + acol[1], SAb + 4096 + tid * 8);
        async_load16(bg + (long)(n0 + brow)    * H_ + bcol,    SBb + tid * 8);
    };

    f32x4 acc[4][4];
    const f32x4 zero4 = {0.f, 0.f, 0.f, 0.f};
#pragma unroll
    for (int i = 0; i < 4; i++)
#pragma unroll
        for (int j = 0; j < 4; j++) acc[i][j] = zero4;

    const int s4 = (ln16 >> 1) & 3;
    int aoff[4], boff[4];
#pragma unroll
    for (int i = 0; i < 4; i++) {
        aoff[i] = (wr * 64 + i * 16 + ln16) * 32 + (quad ^ s4) * 8;
        boff[i] = (wc * 64 + i * 16 + ln16) * 32 + (quad ^ s4) * 8;
    }

    const int nt = 24;                    // K = 768

    stage(0, 0);
    stage(1, 1);
    asm volatile("s_waitcnt vmcnt(3)" ::: "memory");
    __builtin_amdgcn_sched_barrier(0);
    __builtin_amdgcn_s_barrier();

    int bs = 0;
    for (int t = 0; t < nt; ++t) {
        const int ps = (bs + 2 >= 3) ? bs - 1 : bs + 2;   // (t+2)%3

        bf16x8 af[4], bfr[4];
#pragma unroll
        for (int i = 0; i < 4; i++) af[i]  = *(const bf16x8*)&LB[bs * 8192 + aoff[i]];
#pragma unroll
        for (int j = 0; j < 4; j++) bfr[j] = *(const bf16x8*)&LB[24576 + bs * 4096 + boff[j]];
        if (t + 2 < nt) stage(t + 2, ps);

        __builtin_amdgcn_s_setprio(1);
#pragma unroll
        for (int i = 0; i < 4; i++)
#pragma unroll
            for (int j = 0; j < 4; j++)
                acc[i][j] = __builtin_amdgcn_mfma_f32_16x16x32_bf16(af[i], bfr[j], acc[i][j], 0, 0, 0);
        __builtin_amdgcn_s_setprio(0);

        if (t + 2 < nt)       { asm volatile("s_waitcnt vmcnt(3)" ::: "memory"); }
        else if (t + 1 < nt)  { asm volatile("s_waitcnt vmcnt(0)" ::: "memory"); }
        __builtin_amdgcn_sched_barrier(0);
        if (t + 1 < nt) __builtin_amdgcn_s_barrier();
        bs = (bs + 1 == 3) ? 0 : bs + 1;
    }

    // ---- epilogue: LDS-pack then coalesced 128B writes ----
    __syncthreads();                       // all waves done reading SA/SB
    bf16* scr = &LB[wave * 4608];          // 64 x 72 elems per wave

    const int cs0  = n0 + wc * 64;         // 64-aligned -> whole band = one head
    const int sec  = (cs0 >= 1536) ? 2 : ((cs0 >= 768) ? 1 : 0);
    const int head = (cs0 - sec * 768) >> 6;
    bf16* dst = out + (long)sec * M_ * H_;

#pragma unroll
    for (int j = 0; j < 4; j++) {
        const int d_loc = j * 16 + ln16;
        const float bj = bias[cs0 + d_loc];
#pragma unroll
        for (int i = 0; i < 4; i++) {
#pragma unroll
            for (int r = 0; r < 4; r++) {
                const int s_loc = i * 16 + quad * 4 + r;
                const float v = acc[i][j][r] + bj;
                scr[(sec == 2) ? (d_loc * 72 + s_loc) : (s_loc * 72 + d_loc)] = (bf16)v;
            }
        }
    }
    asm volatile("s_waitcnt lgkmcnt(0)" ::: "memory");
    __builtin_amdgcn_sched_barrier(0);

    const int g8 = lane >> 3;              // 0..7
    const int o8 = (lane & 7) * 8;         // 0..56
    if (sec < 2) {
        // [B,NH,S,HD]: 8-lane group writes one row's 128B; 8 rows per it-step
#pragma unroll
        for (int it = 0; it < 8; it++) {
            const int s_loc = it * 8 + g8;
            const int row_s = m0 + wr * 64 + s_loc;
            const int b = row_s >> 9, s = row_s & 511;
            *(bf16x8*)&dst[(((long)(b * NH_ + head)) * S_ + s) * HD_ + o8] =
                *(const bf16x8*)&scr[s_loc * 72 + o8];
        }
    } else {
        // V^T [B,NH,HD,S]: 64-row window is 64-aligned -> single b, s_base
        const int row0 = m0 + wr * 64;
        const int b = row0 >> 9, sb = row0 & 511;
#pragma unroll
        for (int it = 0; it < 8; it++) {
            const int d_loc = it * 8 + g8;
            *(bf16x8*)&dst[(((long)(b * NH_ + head)) * HD_ + d_loc) * S_ + sb + o8] =
                *(const bf16x8*)&scr[d_loc * 72 + o8];
        }
    }
}

// ---------------------------------------------------------------------------
// GEMM C[m,n] = sum_k A[m,k]*Bw[n,k]  (+ epilogue per MODE), bf16, lda=ldb=768
// BM=128 BN=128 BK=32, 256 threads = 4 waves (2x2, 64x64/wave). Triple-buffer
// 48KB -> 3 blocks/CU; grids (128,6)=768 = exact residency multiple.
// REVERTED to round-6 scalar epilogue (measured best 362.8us): row-major
// output segments from one wave are L2-write-combined already; LDS-pack
// (round 7) was neutral-to-negative here. LDS-pack only pays for
// partial-line-at-stride stores (V^T / head-interleaved — see gemm_qkv).
// ---------------------------------------------------------------------------
template<int MODE>
__global__ __launch_bounds__(256, 3) void gemm_bt(
    const bf16* __restrict__ A0, const bf16* __restrict__ A1,
    const bf16* __restrict__ B0, const bf16* __restrict__ B1,
    const float* __restrict__ bias1, const float* __restrict__ bias2,
    const bf16* __restrict__ resid, bf16* __restrict__ out,
    int K, int KSPLIT)
{
    __shared__ __align__(16) bf16 SA[3][128 * 32];   // 3 x 8KB
    __shared__ __align__(16) bf16 SB[3][128 * 32];   // 3 x 8KB

    const int tid  = threadIdx.x;
    const int lane = tid & 63;
    const int wave = tid >> 6;
    const int wr   = wave >> 1;
    const int wc   = wave & 1;
    const int quad = lane >> 4;
    const int ln16 = lane & 15;
    const int m0   = blockIdx.x * 128;
    const int n0   = blockIdx.y * 128;

    int arow[2], acol[2];
#pragma unroll
    for (int q = 0; q < 2; q++) {
        int l = q * 256 + tid;
        int row = l >> 2;
        arow[q] = row;
        acol[q] = ((l & 3) ^ ((row >> 1) & 3)) * 8;
    }

    auto stage = [&](int kt, int bsel) {
        int kk = kt * 32;
        const bf16* ag = (kk < KSPLIT) ? A0 + kk : A1 + (kk - KSPLIT);
        const bf16* bg = (kk < KSPLIT) ? B0 + kk : B1 + (kk - KSPLIT);
        async_load16(ag + (long)(m0 + arow[0]) * H_ + acol[0], &SA[bsel][tid * 8]);
        async_load16(ag + (long)(m0 + arow[1]) * H_ + acol[1], &SA[bsel][2048 + tid * 8]);
        async_load16(bg + (long)(n0 + arow[0]) * H_ + acol[0], &SB[bsel][tid * 8]);
        async_load16(bg + (long)(n0 + arow[1]) * H_ + acol[1], &SB[bsel][2048 + tid * 8]);
    };

    f32x4 acc[4][4];
    const f32x4 zero4 = {0.f, 0.f, 0.f, 0.f};
#pragma unroll
    for (int i = 0; i < 4; i++)
#pragma unroll
        for (int j = 0; j < 4; j++) acc[i][j] = zero4;

    const int s4 = (ln16 >> 1) & 3;
    int aoff[4], boff[4];
#pragma unroll
    for (int i = 0; i < 4; i++) {
        aoff[i] = (wr * 64 + i * 16 + ln16) * 32 + (quad ^ s4) * 8;
        boff[i] = (wc * 64 + i * 16 + ln16) * 32 + (quad ^ s4) * 8;
    }

    const int nt = K >> 5;

    stage(0, 0);
    stage(1, 1);
    asm volatile("s_waitcnt vmcnt(4)" ::: "memory");
    __builtin_amdgcn_sched_barrier(0);
    __builtin_amdgcn_s_barrier();

    int bs = 0;
    for (int t = 0; t < nt; ++t) {
        const int ps = (bs + 2 >= 3) ? bs - 1 : bs + 2;

        bf16x8 af[4], bfr[4];
#pragma unroll
        for (int i = 0; i < 4; i++) af[i]  = *(const bf16x8*)&SA[bs][aoff[i]];
#pragma unroll
        for (int j = 0; j < 4; j++) bfr[j] = *(const bf16x8*)&SB[bs][boff[j]];
        if (t + 2 < nt) stage(t + 2, ps);

        __builtin_amdgcn_s_setprio(1);
#pragma unroll
        for (int i = 0; i < 4; i++)
#pragma unroll
            for (int j = 0; j < 4; j++)
                acc[i][j] = __builtin_amdgcn_mfma_f32_16x16x32_bf16(af[i], bfr[j], acc[i][j], 0, 0, 0);
        __builtin_amdgcn_s_setprio(0);

        if (t + 2 < nt)       { asm volatile("s_waitcnt vmcnt(4)" ::: "memory"); }
        else if (t + 1 < nt)  { asm volatile("s_waitcnt vmcnt(0)" ::: "memory"); }
        __builtin_amdgcn_sched_barrier(0);
        if (t + 1 < nt) __builtin_amdgcn_s_barrier();
        bs = (bs + 1 == 3) ? 0 : bs + 1;
    }

    const int c_r = quad * 4;
    const int c_c = ln16;

#pragma unroll
    for (int j = 0; j < 4; j++) {
        const int col = n0 + wc * 64 + j * 16 + c_c;
        float bias = bias1[col];
        if (MODE == 0) bias += bias2[col];
#pragma unroll
        for (int i = 0; i < 4; i++) {
#pragma unroll
            for (int r = 0; r < 4; r++) {
                const int row = m0 + wr * 64 + i * 16 + c_r + r;
                float v = acc[i][j][r] + bias;
                if (MODE == 0) {
                    v = 0.5f * v * (1.0f + erff(v * 0.70710678118654752f));
                    out[(long)row * H_ + col] = (bf16)v;
                } else {
                    v += (float)resid[(long)row * H_ + col];
                    out[(long)row * H_ + col] = (bf16)v;
                }
            }
        }
    }
}

// ---------------------------------------------------------------------------
// flash attention, transposed-score form.
// NEW (round 8): softmax VALU diet —
//  (1) exp2 domain: scores pre-scaled by 0.125*log2(e), all exps are native
//      v_exp_f32 (deletes the hidden v_mul inside every __expf; ~34/kc/lane).
//  (2) T13 defer-max: skip the O,l rescale when __all(cm - mo <= 8); P is
//      then bounded by 2^8 (safe: fp32 l/O accum, bf16 P keeps rel. error).
//      First kc always rescales (mo = -1e30). Wave-uniform branch (no div).
// ---------------------------------------------------------------------------
#define QP 72   // LDS row stride (elems): 144 B, 16B-aligned

__global__ __launch_bounds__(256) void attn_kernel(
    const bf16* __restrict__ q, const bf16* __restrict__ k,
    const bf16* __restrict__ vt, bf16* __restrict__ ctx)
{
    __shared__ __align__(16) bf16 Qs[64 * QP];
    __shared__ __align__(16) bf16 Ks[64 * QP];
    __shared__ __align__(16) bf16 Vt[64 * QP];      // V^T chunk: [d][t]
    __shared__ __align__(16) bf16 Ps[4][16 * QP];   // per-wave P: [q][t]

    const int tid  = threadIdx.x;
    const int lane = tid & 63;
    const int w    = tid >> 6;
    const int quad = lane >> 4;
    const int ln16 = lane & 15;

    const int bid = blockIdx.x;
    const int qt  = bid / 384;          // qt-major: same g -> same XCD (384%8==0)
    const int g   = bid - qt * 384;
    const int b   = g / 12;
    const int h   = g - b * 12;
    const long base = ((long)(b * NH_ + h)) * S_ * HD_;

    const int r0 = tid >> 2;            // row 0..63
    const int e0 = (tid & 3) * 16;      // col elems 0,16,32,48

    {
        const bf16* qg = q + base + (long)qt * 64 * HD_;
        *(uint4*)&Qs[r0 * QP + e0]     = *(const uint4*)&qg[r0 * HD_ + e0];
        *(uint4*)&Qs[r0 * QP + e0 + 8] = *(const uint4*)&qg[r0 * HD_ + e0 + 8];
    }
    const bf16* kg = k  + base;
    const bf16* vg = vt + base;
    uint4 kr0 = *(const uint4*)&kg[r0 * HD_ + e0];
    uint4 kr1 = *(const uint4*)&kg[r0 * HD_ + e0 + 8];
    uint4 vr0 = *(const uint4*)&vg[(long)r0 * S_ + e0];
    uint4 vr1 = *(const uint4*)&vg[(long)r0 * S_ + e0 + 8];
    __syncthreads();

    const bf16x8 bq0 = *(const bf16x8*)&Qs[(w * 16 + ln16) * QP + quad * 8];
    const bf16x8 bq1 = *(const bf16x8*)&Qs[(w * 16 + ln16) * QP + 32 + quad * 8];

    f32x4 O[4];
    const f32x4 zero4 = {0.f, 0.f, 0.f, 0.f};
#pragma unroll
    for (int t = 0; t < 4; t++) O[t] = zero4;
    float mo = -1e30f, l = 0.f;

    const float SCL = 0.18033688011112042f;   // 0.125 * log2(e)

    for (int kc = 0; kc < 8; kc++) {
        __syncthreads();
        *(uint4*)&Ks[r0 * QP + e0]     = kr0;
        *(uint4*)&Ks[r0 * QP + e0 + 8] = kr1;
        *(uint4*)&Vt[r0 * QP + e0]     = vr0;
        *(uint4*)&Vt[r0 * QP + e0 + 8] = vr1;
        {
            int kcn = (kc < 7) ? kc + 1 : 7;
            kr0 = *(const uint4*)&kg[(long)kcn * 64 * HD_ + r0 * HD_ + e0];
            kr1 = *(const uint4*)&kg[(long)kcn * 64 * HD_ + r0 * HD_ + e0 + 8];
            vr0 = *(const uint4*)&vg[(long)r0 * S_ + kcn * 64 + e0];
            vr1 = *(const uint4*)&vg[(long)r0 * S_ + kcn * 64 + e0 + 8];
        }
        __syncthreads();

        f32x4 sc[4];
#pragma unroll
        for (int i = 0; i < 4; i++) {
            bf16x8 a0 = *(const bf16x8*)&Ks[(i * 16 + ln16) * QP + quad * 8];
            bf16x8 a1 = *(const bf16x8*)&Ks[(i * 16 + ln16) * QP + 32 + quad * 8];
            sc[i] = zero4;
            sc[i] = __builtin_amdgcn_mfma_f32_16x16x32_bf16(a0, bq0, sc[i], 0, 0, 0);
            sc[i] = __builtin_amdgcn_mfma_f32_16x16x32_bf16(a1, bq1, sc[i], 0, 0, 0);
        }

        float cm = -1e30f;
#pragma unroll
        for (int i = 0; i < 4; i++)
#pragma unroll
            for (int r = 0; r < 4; r++) {
                float s = sc[i][r] * SCL;     // exp2 domain
                sc[i][r] = s;
                cm = fmaxf(cm, s);
            }
        cm = fmaxf(cm, __shfl_xor(cm, 16));
        cm = fmaxf(cm, __shfl_xor(cm, 32));

        // T13 defer-max: only rescale when the running max grew by > 8
        // (exp2 domain -> deferred P bounded by 2^8 = 256; fp32 accum safe).
        if (!__all(cm - mo <= 8.0f)) {
            float mn = fmaxf(mo, cm);
            float alpha = exp2f(mo - mn);
            l *= alpha;
#pragma unroll
            for (int t = 0; t < 4; t++)
#pragma unroll
                for (int r = 0; r < 4; r++) O[t][r] *= alpha;
            mo = mn;
        }

        float rs = 0.f;
#pragma unroll
        for (int i = 0; i < 4; i++) {
            bf16x4 pk;
#pragma unroll
            for (int r = 0; r < 4; r++) {
                float p = exp2f(sc[i][r] - mo);   // native v_exp_f32
                rs += p;
                pk[r] = (bf16)p;
            }
            *(bf16x4*)&Ps[w][ln16 * QP + i * 16 + quad * 4] = pk;
        }
        rs += __shfl_xor(rs, 16);
        rs += __shfl_xor(rs, 32);
        l  += rs;

        bf16x8 bp0 = *(const bf16x8*)&Ps[w][ln16 * QP + quad * 8];
        bf16x8 bp1 = *(const bf16x8*)&Ps[w][ln16 * QP + 32 + quad * 8];
#pragma unroll
        for (int dt = 0; dt < 4; dt++) {
            bf16x8 a0 = *(const bf16x8*)&Vt[(dt * 16 + ln16) * QP + quad * 8];
            bf16x8 a1 = *(const bf16x8*)&Vt[(dt * 16 + ln16) * QP + 32 + quad * 8];
            O[dt] = __builtin_amdgcn_mfma_f32_16x16x32_bf16(a0, bp0, O[dt], 0, 0, 0);
            O[dt] = __builtin_amdgcn_mfma_f32_16x16x32_bf16(a1, bp1, O[dt], 0, 0, 0);
        }
    }

    {
        float inv = 1.0f / l;
#pragma unroll
        for (int dt = 0; dt < 4; dt++) {
            bf16x4 ov;
#pragma unroll
            for (int r = 0; r < 4; r++) ov[r] = (bf16)(O[dt][r] * inv);
            *(bf16x4*)&Qs[(w * 16 + ln16) * QP + dt * 16 + quad * 4] = ov;
        }
    }
    __syncthreads();
    {
        uint4 o0 = *(const uint4*)&Qs[r0 * QP + e0];
        uint4 o1 = *(const uint4*)&Qs[r0 * QP + e0 + 8];
        bf16* cg = ctx + ((long)(b * S_ + qt * 64 + r0)) * H_ + h * HD_;
        *(uint4*)&cg[e0]     = o0;
        *(uint4*)&cg[e0 + 8] = o1;
    }
}

// ---------------------------------------------------------------------------
// layernorm: one wave per row; bf16 in, fp32 out
// ---------------------------------------------------------------------------
__global__ __launch_bounds__(256) void ln_kernel(
    const bf16* __restrict__ y, const float* __restrict__ g,
    const float* __restrict__ be, float* __restrict__ out)
{
    const int lane = threadIdx.x & 63;
    const int w    = threadIdx.x >> 6;
    const long row = (long)blockIdx.x * 4 + w;
    const bf16* yr = y + row * H_;

    float x[12];
    float sum = 0.f, ss = 0.f;
#pragma unroll
    for (int j = 0; j < 12; j++) {
        x[j] = (float)yr[j * 64 + lane];
        sum += x[j];
        ss  += x[j] * x[j];
    }
#pragma unroll
    for (int m = 1; m < 64; m <<= 1) {
        sum += __shfl_xor(sum, m);
        ss  += __shfl_xor(ss, m);
    }
    const float mu  = sum * (1.0f / 768.0f);
    float var = ss * (1.0f / 768.0f) - mu * mu;
    const float rs = rsqrtf(fmaxf(var, 0.f) + 1e-12f);
#pragma unroll
    for (int j = 0; j < 12; j++) {
        int c = j * 64 + lane;
        out[row * H_ + c] = (x[j] - mu) * rs * g[c] + be[c];
    }
}

// ---------------------------------------------------------------------------
extern "C" void kernel_launch(void* const* d_in, const int* in_sizes, int n_in,
                              void* d_out, int out_size, void* d_ws, size_t ws_size,
                              hipStream_t stream)
{
    const float* hidden = (const float*)d_in[0];
    const float* ce     = (const float*)d_in[1];
    const int*   cc     = (const int*)d_in[2];
    const int*   vm     = (const int*)d_in[3];
    const float* Wd     = (const float*)d_in[4];
    const float* bd     = (const float*)d_in[5];
    const float* Wc     = (const float*)d_in[6];
    const float* bc     = (const float*)d_in[7];
    const float* Wq     = (const float*)d_in[8];
    const float* bq     = (const float*)d_in[9];
    const float* Wk     = (const float*)d_in[10];
    const float* bk     = (const float*)d_in[11];
    const float* Wv     = (const float*)d_in[12];
    const float* bv     = (const float*)d_in[13];
    const float* Wo     = (const float*)d_in[14];
    const float* bo     = (const float*)d_in[15];
    const float* lng    = (const float*)d_in[16];
    const float* lnb    = (const float*)d_in[17];

    // ---- workspace layout (bf16 elems; total ~102.8 MB) ----
    const long NE = (long)M_ * H_;
    bf16* ws   = (bf16*)d_ws;
    bf16* hbuf = ws;                          // gelu out / resid / y
    bf16* qkv  = ws + NE;                     // qb,kb,vb contiguous
    bf16* hbf  = qkv;                         // hbf over qb (dead before QKV writes)
    bf16* hcol = qkv + NE;                    // hcol over kb
    bf16* qb   = qkv;
    bf16* kb   = qkv + NE;
    bf16* vb   = qkv + 2 * NE;                // V^T layout [B,NH,HD,S]
    bf16* wpack = ws + 4 * NE;
    const bf16* Wd_b  = wpack;
    const bf16* Wc_b  = wpack + 589824;
    const bf16* Wq_b  = wpack + 1179648;      // Wq,Wk,Wv contiguous: 2304x768
    const bf16* Wo_b  = wpack + 2949120;
    float* bqkv = (float*)(wpack + 3538944);
    bf16* ctx = (bf16*)d_out;                 // borrow d_out (dead before LN)

    cvt_kernel<<<14018, 256, 0, stream>>>(hidden, ce, cc, vm, Wd, Wc, Wq, Wk, Wv, Wo,
                                          bq, bk, bv, hbf, hcol, wpack, bqkv);

    dim3 g6(M_ / 128, 6);
    gemm_bt<0><<<g6, 256, 0, stream>>>(hbf, hcol, Wd_b, Wc_b, bd, bc, nullptr, hbuf, 2 * H_, H_);
    gemm_qkv<<<dim3(M_ / 256, 18), 512, 0, stream>>>(hbuf, Wq_b, bqkv, qkv);
    attn_kernel<<<3072, 256, 0, stream>>>(qb, kb, vb, ctx);
    gemm_bt<2><<<g6, 256, 0, stream>>>(ctx, ctx, Wo_b, Wo_b, bo, nullptr, hbuf, hbuf, H_, H_);
    ln_kernel<<<M_ / 4, 256, 0, stream>>>(hbuf, lng, lnb, (float*)d_out);
}